// Round 8
// baseline (1097.124 us; speedup 1.0000x reference)
//
#include <hip/hip_runtime.h>
#include <stdint.h>
#include <math.h>

// Match numpy's non-fused multiply-add rounding: a wrong argmin or a boundary
// mask flip cascades into O(1) output error. R1-R7 passed with absmax 0.0
// using exactly these expression forms — keep them everywhere.
#pragma clang fp contract(off)

#define BLOCK 1024
#define NW (BLOCK / 64)
#define PT 8                     // points/thread/step in full passes (slab-major)
#define PB 4                     // entries/thread/step in block near-engine
#define MAX_ITERS 50
#define NEAR_CAP 9472            // LDS SoA capacity (16 B/entry)
#define SOLO_CAP 2048            // below this, wave 0 runs alone
#define HB 4096                  // d2 histogram bins (top 12 bits of f32)
#define EPS_NORM 1e-8f
#define EPS_SEP (-1e-6f)
#define CMD_REFILL 1
#define CMD_EXIT 2

// R8: near-set algorithm. R6/R7 evidence: ~9 full-N scans/block (Wendel decay
// keeps counts >65k until k~7), each streaming 2.4 MB from L2 -> the scans
// dominate. The planes depend only on the closest survivor, and far points
// matter only after all nearer points die. So: 2 full passes (d2 histogram ->
// threshold; collect nearest ~NEAR_CAP coords+idx into LDS SoA + exact global
// argmin over ALL survivors), then all iterations run on the LDS near set.
// When the near set empties, a refill (same 2-pass routine + stored-plane
// early-exit tests, 4 planes register-chunked) reconstructs the exact
// survivor set (~1 refill/block expected). Waves 1-15 park at a barrier
// command protocol during the solo phase so refills stay parallel.
__global__ __launch_bounds__(BLOCK) void convex_plane_kernel(
    const float* __restrict__ pc, const float* __restrict__ tg,
    float* __restrict__ out, int N, int M, int stepsA)
{
    extern __shared__ uint32_t smem[];
    const int tid  = threadIdx.x;
    const int lane = tid & 63;
    const int wv   = tid >> 6;
    const int m    = blockIdx.x;

    float* sx     = (float*)smem;                 // [NEAR_CAP]
    float* sy     = sx + NEAR_CAP;                // [NEAR_CAP]
    float* sz     = sy + NEAR_CAP;                // [NEAR_CAP]
    int*   sid    = (int*)(sz + NEAR_CAP);        // [NEAR_CAP]
    float* planes = (float*)(sid + NEAR_CAP);     // [52*4] padded, 16B-aligned
    float* red_d  = planes + 52 * 4;              // [NW]
    float* red_x  = red_d + NW;                   // [NW]
    float* red_y  = red_x + NW;                   // [NW]
    float* red_z  = red_y + NW;                   // [NW]
    int*   red_i  = (int*)(red_z + NW);           // [NW]
    int*   wsum   = red_i + NW;                   // [NW]
    int*   ibc    = wsum + NW;                    // [6] {idx,ncount,Kthr,cmd,totSurv,karg}
    float* fbc    = (float*)(ibc + 6);            // [3] argmin coords
    int*   cur    = (int*)(fbc + 3);              // [1] append cursor
    int*   hist   = (int*)sx;                     // aliases sx during buildNear
    const float4* pl4 = (const float4*)planes;

    const float tx = tg[3*m+0], ty = tg[3*m+1], tz = tg[3*m+2];
    const float t2 = tx*tx + ty*ty + tz*tz;

    float* out_a = out;
    float* out_b = out + (size_t)MAX_ITERS * (size_t)M * 3;

    // pad planes: {0,0,0,+inf} never separates (dt = -inf < EPS_SEP), so the
    // refill's 4-plane register chunks can always test a full group of 4.
    if (tid < 52) {
        planes[4*tid+0] = 0.f; planes[4*tid+1] = 0.f;
        planes[4*tid+2] = 0.f; planes[4*tid+3] = INFINITY;
    }

    // block-wide: lexicographic (d2,idx) argmin + coords + survivor-total;
    // results in ibc/fbc for ALL threads (barrier-protected).
    auto finishC = [&](float dmin, int imin, float mx, float my, float mz,
                       int mycnt) {
        #pragma unroll
        for (int off = 32; off > 0; off >>= 1) {
            float od = __shfl_down(dmin, off, 64);
            int   oi = __shfl_down(imin, off, 64);
            float ox = __shfl_down(mx, off, 64);
            float oy = __shfl_down(my, off, 64);
            float oz = __shfl_down(mz, off, 64);
            int   oc = __shfl_down(mycnt, off, 64);
            if (od < dmin || (od == dmin && oi < imin)) {
                dmin = od; imin = oi; mx = ox; my = oy; mz = oz;
            }
            mycnt += oc;
        }
        if (lane == 0) {
            red_d[wv] = dmin; red_i[wv] = imin;
            red_x[wv] = mx; red_y[wv] = my; red_z[wv] = mz; wsum[wv] = mycnt;
        }
        __syncthreads();
        if (wv == 0) {
            float bd = (lane < NW) ? red_d[lane] : INFINITY;
            int   bi = (lane < NW) ? red_i[lane] : 0;
            float bx = (lane < NW) ? red_x[lane] : 0.f;
            float by = (lane < NW) ? red_y[lane] : 0.f;
            float bz = (lane < NW) ? red_z[lane] : 0.f;
            int   c  = (lane < NW) ? wsum[lane]  : 0;
            #pragma unroll
            for (int off = 8; off > 0; off >>= 1) {
                float od = __shfl_down(bd, off, 64);
                int   oi = __shfl_down(bi, off, 64);
                float ox = __shfl_down(bx, off, 64);
                float oy = __shfl_down(by, off, 64);
                float oz = __shfl_down(bz, off, 64);
                int   oc = __shfl_down(c, off, 64);
                if (od < bd || (od == bd && oi < bi)) {
                    bd = od; bi = oi; bx = ox; by = oy; bz = oz;
                }
                c += oc;
            }
            if (lane == 0) {
                ibc[0] = bi; ibc[1] = cur[0]; ibc[4] = c;
                fbc[0] = bx; fbc[1] = by; fbc[2] = bz;
            }
        }
        __syncthreads();
    };

    // Unified build/refill (ALL waves): pass A histograms d2 of survivors of
    // planes[0..kplanes); threshold = nearest <=NEAR_CAP; pass B collects the
    // near set into SoA and the exact argmin over ALL survivors.
    auto buildNear = [&](int kplanes) {
        for (int h = tid; h < HB; h += BLOCK) hist[h] = 0;
        __syncthreads();
        // ---- pass A ----
        for (int s = 0; s < stepsA; ++s) {
            const int ib = s * PT * BLOCK + tid;
            uint32_t live = 0;
            float px[PT], py[PT], pz[PT];
            #pragma unroll
            for (int j = 0; j < PT; ++j) {
                const int i = ib + j * BLOCK;
                if (i < N) {
                    live |= (1u << j);
                    const float* p = pc + 3 * (size_t)i;
                    px[j] = p[0]; py[j] = p[1]; pz[j] = p[2];
                }
            }
            for (int q0 = 0; q0 < kplanes && live; q0 += 4) {
                float4 a0 = pl4[q0], a1 = pl4[q0+1], a2 = pl4[q0+2], a3 = pl4[q0+3];
                #pragma unroll
                for (int j = 0; j < PT; ++j) if ((live >> j) & 1u) {
                    float d0 = a0.x*px[j] + a0.y*py[j] + a0.z*pz[j] - a0.w;
                    float d1 = a1.x*px[j] + a1.y*py[j] + a1.z*pz[j] - a1.w;
                    float d2t = a2.x*px[j] + a2.y*py[j] + a2.z*pz[j] - a2.w;
                    float d3 = a3.x*px[j] + a3.y*py[j] + a3.z*pz[j] - a3.w;
                    if (d0 >= EPS_SEP || d1 >= EPS_SEP || d2t >= EPS_SEP || d3 >= EPS_SEP)
                        live &= ~(1u << j);
                }
            }
            #pragma unroll
            for (int j = 0; j < PT; ++j) if ((live >> j) & 1u) {
                float p2 = px[j]*px[j] + py[j]*py[j] + pz[j]*pz[j];
                float tp = tx*px[j] + ty*py[j] + tz*pz[j];
                float d2 = t2 + p2 - 2.0f*tp;        // reference's exact form
                atomicAdd(&hist[(int)(__float_as_uint(d2) >> 20)], 1);
            }
        }
        __syncthreads();
        // ---- threshold: largest prefix with cumulative <= NEAR_CAP ----
        const int b0 = tid * (HB / BLOCK);           // 4 bins/thread
        const int h0 = hist[b0], h1 = hist[b0+1], h2 = hist[b0+2], h3 = hist[b0+3];
        const int ls = h0 + h1 + h2 + h3;
        int incl = ls;
        #pragma unroll
        for (int off = 1; off < 64; off <<= 1) {
            int o = __shfl_up(incl, off, 64);
            if (lane >= off) incl += o;
        }
        if (lane == 63) wsum[wv] = incl;
        if (tid == 0) ibc[2] = HB;                   // default: keep all
        __syncthreads();
        if (wv == 0 && lane < NW) {
            int v = wsum[lane];
            int i2 = v;
            #pragma unroll
            for (int off = 1; off < NW; off <<= 1) {
                int o = __shfl_up(i2, off, 64);
                if (lane >= off) i2 += o;
            }
            wsum[lane] = i2 - v;                     // exclusive wave base
        }
        __syncthreads();
        int ex = wsum[wv] + incl - ls;               // excl prefix before b0
        int c = ex;                                  // exactly one crossing
        if (c <= NEAR_CAP && c + h0 > NEAR_CAP) ibc[2] = b0;
        c += h0; if (c <= NEAR_CAP && c + h1 > NEAR_CAP) ibc[2] = b0 + 1;
        c += h1; if (c <= NEAR_CAP && c + h2 > NEAR_CAP) ibc[2] = b0 + 2;
        c += h2; if (c <= NEAR_CAP && c + h3 > NEAR_CAP) ibc[2] = b0 + 3;
        if (tid == 0) cur[0] = 0;
        __syncthreads();                             // hist (sx) dead after this
        const int Kthr = ibc[2];
        // ---- pass B: collect near + argmin over ALL survivors ----
        float dmin = INFINITY; int imin = 0;
        float mx = 0.f, my = 0.f, mz = 0.f;
        int mycnt = 0;
        for (int s = 0; s < stepsA; ++s) {
            const int ib = s * PT * BLOCK + tid;
            uint32_t live = 0;
            float px[PT], py[PT], pz[PT];
            #pragma unroll
            for (int j = 0; j < PT; ++j) {
                const int i = ib + j * BLOCK;
                if (i < N) {
                    live |= (1u << j);
                    const float* p = pc + 3 * (size_t)i;
                    px[j] = p[0]; py[j] = p[1]; pz[j] = p[2];
                }
            }
            for (int q0 = 0; q0 < kplanes && live; q0 += 4) {
                float4 a0 = pl4[q0], a1 = pl4[q0+1], a2 = pl4[q0+2], a3 = pl4[q0+3];
                #pragma unroll
                for (int j = 0; j < PT; ++j) if ((live >> j) & 1u) {
                    float d0 = a0.x*px[j] + a0.y*py[j] + a0.z*pz[j] - a0.w;
                    float d1 = a1.x*px[j] + a1.y*py[j] + a1.z*pz[j] - a1.w;
                    float d2t = a2.x*px[j] + a2.y*py[j] + a2.z*pz[j] - a2.w;
                    float d3 = a3.x*px[j] + a3.y*py[j] + a3.z*pz[j] - a3.w;
                    if (d0 >= EPS_SEP || d1 >= EPS_SEP || d2t >= EPS_SEP || d3 >= EPS_SEP)
                        live &= ~(1u << j);
                }
            }
            mycnt += (int)__popc(live);
            #pragma unroll
            for (int j = 0; j < PT; ++j) {
                bool nearkeep = false;
                float d2 = 0.f;
                if ((live >> j) & 1u) {
                    float p2 = px[j]*px[j] + py[j]*py[j] + pz[j]*pz[j];
                    float tp = tx*px[j] + ty*py[j] + tz*pz[j];
                    d2 = t2 + p2 - 2.0f*tp;          // bitwise same as pass A
                    const int i = ib + j * BLOCK;
                    if (d2 < dmin || (d2 == dmin && i < imin)) {
                        dmin = d2; imin = i; mx = px[j]; my = py[j]; mz = pz[j];
                    }
                    nearkeep = ((int)(__float_as_uint(d2) >> 20) < Kthr);
                }
                unsigned long long bal = __ballot(nearkeep);
                if (bal) {                            // wave-uniform
                    int base = 0;
                    if (lane == 0) base = atomicAdd(cur, (int)__popcll(bal));
                    base = __shfl(base, 0, 64);
                    if (nearkeep) {
                        int pos = base + (int)__popcll(bal & ((1ull << lane) - 1ull));
                        if (pos < NEAR_CAP) {
                            sx[pos] = px[j]; sy[pos] = py[j]; sz[pos] = pz[j];
                            sid[pos] = ib + j * BLOCK;
                        }
                    }
                }
            }
        }
        finishC(dmin, imin, mx, my, mz, mycnt);
    };

    // Block near-engine: cut SoA in place (scanB-proven discipline).
    auto scanN = [&](int count, float ax, float ay, float az, float b) {
        if (tid == 0) cur[0] = 0;
        __syncthreads();
        float dmin = INFINITY; int imin = 0;
        float mx = 0.f, my = 0.f, mz = 0.f;
        const int per = BLOCK * PB;
        const int bsteps = (count + per - 1) / per;
        for (int s = 0; s < bsteps; ++s) {
            float X[PB], Y[PB], Z[PB], D[PB]; int J[PB];
            uint32_t keepm = 0;
            #pragma unroll
            for (int q = 0; q < PB; ++q) {
                const int e = s * per + q * BLOCK + tid;  // lane-stride 1
                if (e < count) {
                    float px = sx[e], py = sy[e], pz = sz[e];
                    X[q] = px; Y[q] = py; Z[q] = pz; J[q] = sid[e];
                    float dt = ax*px + ay*py + az*pz - b;
                    if (dt < EPS_SEP) {
                        keepm |= (1u << q);
                        float p2 = px*px + py*py + pz*pz;
                        float tp = tx*px + ty*py + tz*pz;
                        D[q] = t2 + p2 - 2.0f*tp;
                    }
                }
            }
            __syncthreads();                         // reads before appends
            int c = (int)__popc(keepm);
            int incl = c;
            #pragma unroll
            for (int off = 1; off < 64; off <<= 1) {
                int o = __shfl_up(incl, off, 64);
                if (lane >= off) incl += o;
            }
            const int excl = incl - c;
            const int tot  = __shfl(incl, 63, 64);
            int wb = 0;
            if (lane == 0) wb = atomicAdd(cur, tot);
            wb = __shfl(wb, 0, 64);
            int pos = wb + excl;
            #pragma unroll
            for (int q = 0; q < PB; ++q) if ((keepm >> q) & 1u) {
                sx[pos] = X[q]; sy[pos] = Y[q]; sz[pos] = Z[q]; sid[pos] = J[q];
                if (D[q] < dmin || (D[q] == dmin && J[q] < imin)) {
                    dmin = D[q]; imin = J[q]; mx = X[q]; my = Y[q]; mz = Z[q];
                }
                ++pos;
            }
        }
        finishC(dmin, imin, mx, my, mz, 0);
    };

    // ---- initial build (kplanes = 0) ----
    buildNear(0);
    int   ncount = ibc[1];
    float ccx = fbc[0], ccy = fbc[1], ccz = fbc[2];
    int k = 0;

    // ---- BLOCK mode ----
    for (;;) {
        if (ncount == 0) {
            buildNear(k);                            // planes 0..k-1 stored
            ncount = ibc[1];
            ccx = fbc[0]; ccy = fbc[1]; ccz = fbc[2];
            if (ibc[4] == 0) {                       // truly empty: pc[0] tail
                const float c0 = pc[0], c1 = pc[1], c2 = pc[2];
                const float vx = c0 - tx, vy = c1 - ty, vz = c2 - tz;
                const float nrm = sqrtf(vx*vx + vy*vy + vz*vz);
                const float den = nrm + EPS_NORM;
                const float ax = vx / den, ay = vy / den, az = vz / den;
                const float b  = ax*c0 + ay*c1 + az*c2;
                for (int q = tid; q < MAX_ITERS - k; q += BLOCK) {
                    const int kk = k + q;
                    const size_t oa = ((size_t)kk * M + m) * 3;
                    out_a[oa+0] = ax; out_a[oa+1] = ay; out_a[oa+2] = az;
                    out_b[(size_t)kk * M + m] = b;
                }
                return;
            }
        }
        if (ncount > 0 && ncount <= SOLO_CAP) break; // -> solo
        const float vx = ccx - tx, vy = ccy - ty, vz = ccz - tz;
        const float nrm = sqrtf(vx*vx + vy*vy + vz*vz);
        const float den = nrm + EPS_NORM;
        const float ax = vx / den, ay = vy / den, az = vz / den;
        const float b  = ax*ccx + ay*ccy + az*ccz;   // b = sum(a * closest)
        if (tid == 0) {
            const size_t oa = ((size_t)k * M + m) * 3;
            out_a[oa+0] = ax; out_a[oa+1] = ay; out_a[oa+2] = az;
            out_b[(size_t)k * M + m] = b;
            planes[4*k+0] = ax; planes[4*k+1] = ay;
            planes[4*k+2] = az; planes[4*k+3] = b;
        }
        ++k;
        if (k == MAX_ITERS) return;                  // all waves together
        if (ncount > 0) {
            scanN(ncount, ax, ay, az, b);
            ncount = ibc[1];
            ccx = fbc[0]; ccy = fbc[1]; ccz = fbc[2];
        }
    }

    // ---- SOLO mode: waves 1-15 park at the command barrier ----
    if (wv != 0) {
        for (;;) {
            __syncthreads();
            const int c = ibc[3];
            if (c == CMD_EXIT) return;
            buildNear(ibc[5]);                       // CMD_REFILL
        }
    }
    // wave 0:
    int scount = ncount;
    for (;;) {
        if (scount == 0) {
            if (lane == 0) { ibc[3] = CMD_REFILL; ibc[5] = k; }
            __syncthreads();
            buildNear(k);
            scount = ibc[1];
            ccx = fbc[0]; ccy = fbc[1]; ccz = fbc[2];
            if (ibc[4] == 0) {                       // truly empty
                if (lane == 0) ibc[3] = CMD_EXIT;
                __syncthreads();
                const float c0 = pc[0], c1 = pc[1], c2 = pc[2];
                const float vx = c0 - tx, vy = c1 - ty, vz = c2 - tz;
                const float nrm = sqrtf(vx*vx + vy*vy + vz*vz);
                const float den = nrm + EPS_NORM;
                const float ax = vx / den, ay = vy / den, az = vz / den;
                const float b  = ax*c0 + ay*c1 + az*c2;
                for (int q = lane; q < MAX_ITERS - k; q += 64) {
                    const int kk = k + q;
                    const size_t oa = ((size_t)kk * M + m) * 3;
                    out_a[oa+0] = ax; out_a[oa+1] = ay; out_a[oa+2] = az;
                    out_b[(size_t)kk * M + m] = b;
                }
                return;
            }
        }
        const float vx = ccx - tx, vy = ccy - ty, vz = ccz - tz;
        const float nrm = sqrtf(vx*vx + vy*vy + vz*vz);
        const float den = nrm + EPS_NORM;
        const float ax = vx / den, ay = vy / den, az = vz / den;
        const float b  = ax*ccx + ay*ccy + az*ccz;
        if (lane == 0) {
            const size_t oa = ((size_t)k * M + m) * 3;
            out_a[oa+0] = ax; out_a[oa+1] = ay; out_a[oa+2] = az;
            out_b[(size_t)k * M + m] = b;
            planes[4*k+0] = ax; planes[4*k+1] = ay;
            planes[4*k+2] = az; planes[4*k+3] = b;
        }
        ++k;
        if (k == MAX_ITERS) {
            if (lane == 0) ibc[3] = CMD_EXIT;
            __syncthreads();
            return;
        }
        if (scount > 0) {                            // wave-synchronous cut
            float dmin = INFINITY; int imin = 0;
            float mx = 0.f, my = 0.f, mz = 0.f;
            int wcur = 0;
            const int old = scount;
            for (int g0 = 0; g0 < old; g0 += 256) {
                float X[4], Y[4], Z[4], D[4]; int J[4];
                uint32_t km = 0;
                #pragma unroll
                for (int u = 0; u < 4; ++u) {        // read group fully first
                    const int e = g0 + u * 64 + lane;
                    if (e < old) {
                        X[u] = sx[e]; Y[u] = sy[e]; Z[u] = sz[e]; J[u] = sid[e];
                        float dt = ax*X[u] + ay*Y[u] + az*Z[u] - b;
                        if (dt < EPS_SEP) {
                            km |= (1u << u);
                            float p2 = X[u]*X[u] + Y[u]*Y[u] + Z[u]*Z[u];
                            float tp = tx*X[u] + ty*Y[u] + tz*Z[u];
                            D[u] = t2 + p2 - 2.0f*tp;
                        }
                    }
                }
                #pragma unroll
                for (int u = 0; u < 4; ++u) {        // compacted writes after
                    unsigned long long bal = __ballot(((km >> u) & 1u) != 0u);
                    int pos = wcur + (int)__popcll(bal & ((1ull << lane) - 1ull));
                    if ((km >> u) & 1u) {
                        sx[pos] = X[u]; sy[pos] = Y[u]; sz[pos] = Z[u]; sid[pos] = J[u];
                        if (D[u] < dmin || (D[u] == dmin && J[u] < imin)) {
                            dmin = D[u]; imin = J[u]; mx = X[u]; my = Y[u]; mz = Z[u];
                        }
                    }
                    wcur += (int)__popcll(bal);
                }   // writes stay < wcur <= g0+256 = next group's start
            }
            #pragma unroll
            for (int off = 32; off > 0; off >>= 1) {
                float od = __shfl_down(dmin, off, 64);
                int   oi = __shfl_down(imin, off, 64);
                float ox = __shfl_down(mx, off, 64);
                float oy = __shfl_down(my, off, 64);
                float oz = __shfl_down(mz, off, 64);
                if (od < dmin || (od == dmin && oi < imin)) {
                    dmin = od; imin = oi; mx = ox; my = oy; mz = oz;
                }
            }
            ccx = __shfl(mx, 0, 64);
            ccy = __shfl(my, 0, 64);
            ccz = __shfl(mz, 0, 64);
            scount = wcur;                           // uniform across lanes
        }
    }
}

extern "C" void kernel_launch(void* const* d_in, const int* in_sizes, int n_in,
                              void* d_out, int out_size, void* d_ws, size_t ws_size,
                              hipStream_t stream) {
    const float* pc = (const float*)d_in[0];
    const float* tg = (const float*)d_in[1];
    float* out = (float*)d_out;
    const int N = in_sizes[0] / 3;
    const int M = in_sizes[1] / 3;
    const int stepsA = (N + BLOCK * PT - 1) / (BLOCK * PT);

    const size_t words = (size_t)4 * NEAR_CAP        // SoA
                       + 52 * 4                      // padded planes
                       + 4 * NW + NW + NW            // red_* float, red_i, wsum
                       + 6 + 3 + 1;                  // ibc, fbc, cur
    const size_t smem = words * 4;                   // ~153 KB
    hipFuncSetAttribute((const void*)convex_plane_kernel,
                        hipFuncAttributeMaxDynamicSharedMemorySize, (int)smem);
    convex_plane_kernel<<<M, BLOCK, smem, stream>>>(pc, tg, out, N, M, stepsA);
}

// Round 9
// 1093.261 us; speedup vs baseline: 1.0035x; 1.0035x over previous
//
#include <hip/hip_runtime.h>
#include <stdint.h>
#include <math.h>

// Match numpy's non-fused multiply-add rounding: a wrong argmin or a boundary
// mask flip cascades into O(1) output error. R1-R8 passed with absmax 0.0
// using exactly these expression forms — keep them everywhere.
#pragma clang fp contract(off)

#define BLOCK 1024
#define NW (BLOCK / 64)
#define PT 8                     // points/thread/step in full passes (slab-major)
#define PB 4                     // entries/thread/step in block near-engine
#define MAX_ITERS 50
#define NEAR_CAP 9472            // LDS SoA capacity (16 B/entry)
#define SOLO_CAP 2048            // below this, wave 0 runs alone
#define HB 4096                  // d2 histogram bins (top 12 bits of f32)
#define EPS_NORM 1e-8f
#define EPS_SEP (-1e-6f)
#define CMD_REFILL 1
#define CMD_EXIT 2

// R8 post-mortem: the near-set algorithm worked (FETCH == 2 full passes/block
// => near set lasted ~all iterations for most blocks), but plain
// __launch_bounds__(BLOCK) let the compiler cap VGPRs at 64 (8 waves/SIMD
// target) and spill px/py/pz[8] to scratch: 2.1 GB writes + L2/L3 eviction
// => HBM-bound at 3.1 TB/s. Fix: __launch_bounds__(BLOCK, 4) — we run exactly
// 1 block/CU anyway (153 KB LDS), so allow 128 VGPRs. NOTHING else changed.
//
// Algorithm: planes depend only on the closest survivor; far points matter
// only after all nearer ones die. 2 full passes (d2 histogram -> threshold;
// collect nearest <=NEAR_CAP survivors into LDS SoA + exact argmin over ALL
// survivors), then all iterations run on the LDS near set. On empty: refill
// (same 2 passes + stored-plane early-exit tests, 4 planes register-chunked).
// Waves 1-15 park at a barrier command protocol during the solo phase.
__global__ __launch_bounds__(BLOCK, 4) void convex_plane_kernel(
    const float* __restrict__ pc, const float* __restrict__ tg,
    float* __restrict__ out, int N, int M, int stepsA)
{
    extern __shared__ uint32_t smem[];
    const int tid  = threadIdx.x;
    const int lane = tid & 63;
    const int wv   = tid >> 6;
    const int m    = blockIdx.x;

    float* sx     = (float*)smem;                 // [NEAR_CAP]
    float* sy     = sx + NEAR_CAP;                // [NEAR_CAP]
    float* sz     = sy + NEAR_CAP;                // [NEAR_CAP]
    int*   sid    = (int*)(sz + NEAR_CAP);        // [NEAR_CAP]
    float* planes = (float*)(sid + NEAR_CAP);     // [52*4] padded, 16B-aligned
    float* red_d  = planes + 52 * 4;              // [NW]
    float* red_x  = red_d + NW;                   // [NW]
    float* red_y  = red_x + NW;                   // [NW]
    float* red_z  = red_y + NW;                   // [NW]
    int*   red_i  = (int*)(red_z + NW);           // [NW]
    int*   wsum   = red_i + NW;                   // [NW]
    int*   ibc    = wsum + NW;                    // [6] {idx,ncount,Kthr,cmd,totSurv,karg}
    float* fbc    = (float*)(ibc + 6);            // [3] argmin coords
    int*   cur    = (int*)(fbc + 3);              // [1] append cursor
    int*   hist   = (int*)sx;                     // aliases sx during buildNear
    const float4* pl4 = (const float4*)planes;

    const float tx = tg[3*m+0], ty = tg[3*m+1], tz = tg[3*m+2];
    const float t2 = tx*tx + ty*ty + tz*tz;

    float* out_a = out;
    float* out_b = out + (size_t)MAX_ITERS * (size_t)M * 3;

    // pad planes: {0,0,0,+inf} never separates (dt = -inf < EPS_SEP), so the
    // refill's 4-plane register chunks can always test a full group of 4.
    if (tid < 52) {
        planes[4*tid+0] = 0.f; planes[4*tid+1] = 0.f;
        planes[4*tid+2] = 0.f; planes[4*tid+3] = INFINITY;
    }

    // block-wide: lexicographic (d2,idx) argmin + coords + survivor-total;
    // results in ibc/fbc for ALL threads (barrier-protected).
    auto finishC = [&](float dmin, int imin, float mx, float my, float mz,
                       int mycnt) {
        #pragma unroll
        for (int off = 32; off > 0; off >>= 1) {
            float od = __shfl_down(dmin, off, 64);
            int   oi = __shfl_down(imin, off, 64);
            float ox = __shfl_down(mx, off, 64);
            float oy = __shfl_down(my, off, 64);
            float oz = __shfl_down(mz, off, 64);
            int   oc = __shfl_down(mycnt, off, 64);
            if (od < dmin || (od == dmin && oi < imin)) {
                dmin = od; imin = oi; mx = ox; my = oy; mz = oz;
            }
            mycnt += oc;
        }
        if (lane == 0) {
            red_d[wv] = dmin; red_i[wv] = imin;
            red_x[wv] = mx; red_y[wv] = my; red_z[wv] = mz; wsum[wv] = mycnt;
        }
        __syncthreads();
        if (wv == 0) {
            float bd = (lane < NW) ? red_d[lane] : INFINITY;
            int   bi = (lane < NW) ? red_i[lane] : 0;
            float bx = (lane < NW) ? red_x[lane] : 0.f;
            float by = (lane < NW) ? red_y[lane] : 0.f;
            float bz = (lane < NW) ? red_z[lane] : 0.f;
            int   c  = (lane < NW) ? wsum[lane]  : 0;
            #pragma unroll
            for (int off = 8; off > 0; off >>= 1) {
                float od = __shfl_down(bd, off, 64);
                int   oi = __shfl_down(bi, off, 64);
                float ox = __shfl_down(bx, off, 64);
                float oy = __shfl_down(by, off, 64);
                float oz = __shfl_down(bz, off, 64);
                int   oc = __shfl_down(c, off, 64);
                if (od < bd || (od == bd && oi < bi)) {
                    bd = od; bi = oi; bx = ox; by = oy; bz = oz;
                }
                c += oc;
            }
            if (lane == 0) {
                ibc[0] = bi; ibc[1] = cur[0]; ibc[4] = c;
                fbc[0] = bx; fbc[1] = by; fbc[2] = bz;
            }
        }
        __syncthreads();
    };

    // Unified build/refill (ALL waves): pass A histograms d2 of survivors of
    // planes[0..kplanes); threshold = nearest <=NEAR_CAP; pass B collects the
    // near set into SoA and the exact argmin over ALL survivors.
    auto buildNear = [&](int kplanes) {
        for (int h = tid; h < HB; h += BLOCK) hist[h] = 0;
        __syncthreads();
        // ---- pass A ----
        for (int s = 0; s < stepsA; ++s) {
            const int ib = s * PT * BLOCK + tid;
            uint32_t live = 0;
            float px[PT], py[PT], pz[PT];
            #pragma unroll
            for (int j = 0; j < PT; ++j) {
                const int i = ib + j * BLOCK;
                if (i < N) {
                    live |= (1u << j);
                    const float* p = pc + 3 * (size_t)i;
                    px[j] = p[0]; py[j] = p[1]; pz[j] = p[2];
                }
            }
            for (int q0 = 0; q0 < kplanes && live; q0 += 4) {
                float4 a0 = pl4[q0], a1 = pl4[q0+1], a2 = pl4[q0+2], a3 = pl4[q0+3];
                #pragma unroll
                for (int j = 0; j < PT; ++j) if ((live >> j) & 1u) {
                    float d0 = a0.x*px[j] + a0.y*py[j] + a0.z*pz[j] - a0.w;
                    float d1 = a1.x*px[j] + a1.y*py[j] + a1.z*pz[j] - a1.w;
                    float d2t = a2.x*px[j] + a2.y*py[j] + a2.z*pz[j] - a2.w;
                    float d3 = a3.x*px[j] + a3.y*py[j] + a3.z*pz[j] - a3.w;
                    if (d0 >= EPS_SEP || d1 >= EPS_SEP || d2t >= EPS_SEP || d3 >= EPS_SEP)
                        live &= ~(1u << j);
                }
            }
            #pragma unroll
            for (int j = 0; j < PT; ++j) if ((live >> j) & 1u) {
                float p2 = px[j]*px[j] + py[j]*py[j] + pz[j]*pz[j];
                float tp = tx*px[j] + ty*py[j] + tz*pz[j];
                float d2 = t2 + p2 - 2.0f*tp;        // reference's exact form
                atomicAdd(&hist[(int)(__float_as_uint(d2) >> 20)], 1);
            }
        }
        __syncthreads();
        // ---- threshold: largest prefix with cumulative <= NEAR_CAP ----
        const int b0 = tid * (HB / BLOCK);           // 4 bins/thread
        const int h0 = hist[b0], h1 = hist[b0+1], h2 = hist[b0+2], h3 = hist[b0+3];
        const int ls = h0 + h1 + h2 + h3;
        int incl = ls;
        #pragma unroll
        for (int off = 1; off < 64; off <<= 1) {
            int o = __shfl_up(incl, off, 64);
            if (lane >= off) incl += o;
        }
        if (lane == 63) wsum[wv] = incl;
        if (tid == 0) ibc[2] = HB;                   // default: keep all
        __syncthreads();
        if (wv == 0 && lane < NW) {
            int v = wsum[lane];
            int i2 = v;
            #pragma unroll
            for (int off = 1; off < NW; off <<= 1) {
                int o = __shfl_up(i2, off, 64);
                if (lane >= off) i2 += o;
            }
            wsum[lane] = i2 - v;                     // exclusive wave base
        }
        __syncthreads();
        int ex = wsum[wv] + incl - ls;               // excl prefix before b0
        int c = ex;                                  // exactly one crossing
        if (c <= NEAR_CAP && c + h0 > NEAR_CAP) ibc[2] = b0;
        c += h0; if (c <= NEAR_CAP && c + h1 > NEAR_CAP) ibc[2] = b0 + 1;
        c += h1; if (c <= NEAR_CAP && c + h2 > NEAR_CAP) ibc[2] = b0 + 2;
        c += h2; if (c <= NEAR_CAP && c + h3 > NEAR_CAP) ibc[2] = b0 + 3;
        if (tid == 0) cur[0] = 0;
        __syncthreads();                             // hist (sx) dead after this
        const int Kthr = ibc[2];
        // ---- pass B: collect near + argmin over ALL survivors ----
        float dmin = INFINITY; int imin = 0;
        float mx = 0.f, my = 0.f, mz = 0.f;
        int mycnt = 0;
        for (int s = 0; s < stepsA; ++s) {
            const int ib = s * PT * BLOCK + tid;
            uint32_t live = 0;
            float px[PT], py[PT], pz[PT];
            #pragma unroll
            for (int j = 0; j < PT; ++j) {
                const int i = ib + j * BLOCK;
                if (i < N) {
                    live |= (1u << j);
                    const float* p = pc + 3 * (size_t)i;
                    px[j] = p[0]; py[j] = p[1]; pz[j] = p[2];
                }
            }
            for (int q0 = 0; q0 < kplanes && live; q0 += 4) {
                float4 a0 = pl4[q0], a1 = pl4[q0+1], a2 = pl4[q0+2], a3 = pl4[q0+3];
                #pragma unroll
                for (int j = 0; j < PT; ++j) if ((live >> j) & 1u) {
                    float d0 = a0.x*px[j] + a0.y*py[j] + a0.z*pz[j] - a0.w;
                    float d1 = a1.x*px[j] + a1.y*py[j] + a1.z*pz[j] - a1.w;
                    float d2t = a2.x*px[j] + a2.y*py[j] + a2.z*pz[j] - a2.w;
                    float d3 = a3.x*px[j] + a3.y*py[j] + a3.z*pz[j] - a3.w;
                    if (d0 >= EPS_SEP || d1 >= EPS_SEP || d2t >= EPS_SEP || d3 >= EPS_SEP)
                        live &= ~(1u << j);
                }
            }
            mycnt += (int)__popc(live);
            #pragma unroll
            for (int j = 0; j < PT; ++j) {
                bool nearkeep = false;
                float d2 = 0.f;
                if ((live >> j) & 1u) {
                    float p2 = px[j]*px[j] + py[j]*py[j] + pz[j]*pz[j];
                    float tp = tx*px[j] + ty*py[j] + tz*pz[j];
                    d2 = t2 + p2 - 2.0f*tp;          // bitwise same as pass A
                    const int i = ib + j * BLOCK;
                    if (d2 < dmin || (d2 == dmin && i < imin)) {
                        dmin = d2; imin = i; mx = px[j]; my = py[j]; mz = pz[j];
                    }
                    nearkeep = ((int)(__float_as_uint(d2) >> 20) < Kthr);
                }
                unsigned long long bal = __ballot(nearkeep);
                if (bal) {                            // wave-uniform
                    int base = 0;
                    if (lane == 0) base = atomicAdd(cur, (int)__popcll(bal));
                    base = __shfl(base, 0, 64);
                    if (nearkeep) {
                        int pos = base + (int)__popcll(bal & ((1ull << lane) - 1ull));
                        if (pos < NEAR_CAP) {
                            sx[pos] = px[j]; sy[pos] = py[j]; sz[pos] = pz[j];
                            sid[pos] = ib + j * BLOCK;
                        }
                    }
                }
            }
        }
        finishC(dmin, imin, mx, my, mz, mycnt);
    };

    // Block near-engine: cut SoA in place (scanB-proven discipline).
    auto scanN = [&](int count, float ax, float ay, float az, float b) {
        if (tid == 0) cur[0] = 0;
        __syncthreads();
        float dmin = INFINITY; int imin = 0;
        float mx = 0.f, my = 0.f, mz = 0.f;
        const int per = BLOCK * PB;
        const int bsteps = (count + per - 1) / per;
        for (int s = 0; s < bsteps; ++s) {
            float X[PB], Y[PB], Z[PB], D[PB]; int J[PB];
            uint32_t keepm = 0;
            #pragma unroll
            for (int q = 0; q < PB; ++q) {
                const int e = s * per + q * BLOCK + tid;  // lane-stride 1
                if (e < count) {
                    float px = sx[e], py = sy[e], pz = sz[e];
                    X[q] = px; Y[q] = py; Z[q] = pz; J[q] = sid[e];
                    float dt = ax*px + ay*py + az*pz - b;
                    if (dt < EPS_SEP) {
                        keepm |= (1u << q);
                        float p2 = px*px + py*py + pz*pz;
                        float tp = tx*px + ty*py + tz*pz;
                        D[q] = t2 + p2 - 2.0f*tp;
                    }
                }
            }
            __syncthreads();                         // reads before appends
            int c = (int)__popc(keepm);
            int incl = c;
            #pragma unroll
            for (int off = 1; off < 64; off <<= 1) {
                int o = __shfl_up(incl, off, 64);
                if (lane >= off) incl += o;
            }
            const int excl = incl - c;
            const int tot  = __shfl(incl, 63, 64);
            int wb = 0;
            if (lane == 0) wb = atomicAdd(cur, tot);
            wb = __shfl(wb, 0, 64);
            int pos = wb + excl;
            #pragma unroll
            for (int q = 0; q < PB; ++q) if ((keepm >> q) & 1u) {
                sx[pos] = X[q]; sy[pos] = Y[q]; sz[pos] = Z[q]; sid[pos] = J[q];
                if (D[q] < dmin || (D[q] == dmin && J[q] < imin)) {
                    dmin = D[q]; imin = J[q]; mx = X[q]; my = Y[q]; mz = Z[q];
                }
                ++pos;
            }
        }
        finishC(dmin, imin, mx, my, mz, 0);
    };

    // ---- initial build (kplanes = 0) ----
    buildNear(0);
    int   ncount = ibc[1];
    float ccx = fbc[0], ccy = fbc[1], ccz = fbc[2];
    int k = 0;

    // ---- BLOCK mode ----
    for (;;) {
        if (ncount == 0) {
            buildNear(k);                            // planes 0..k-1 stored
            ncount = ibc[1];
            ccx = fbc[0]; ccy = fbc[1]; ccz = fbc[2];
            if (ibc[4] == 0) {                       // truly empty: pc[0] tail
                const float c0 = pc[0], c1 = pc[1], c2 = pc[2];
                const float vx = c0 - tx, vy = c1 - ty, vz = c2 - tz;
                const float nrm = sqrtf(vx*vx + vy*vy + vz*vz);
                const float den = nrm + EPS_NORM;
                const float ax = vx / den, ay = vy / den, az = vz / den;
                const float b  = ax*c0 + ay*c1 + az*c2;
                for (int q = tid; q < MAX_ITERS - k; q += BLOCK) {
                    const int kk = k + q;
                    const size_t oa = ((size_t)kk * M + m) * 3;
                    out_a[oa+0] = ax; out_a[oa+1] = ay; out_a[oa+2] = az;
                    out_b[(size_t)kk * M + m] = b;
                }
                return;
            }
        }
        if (ncount > 0 && ncount <= SOLO_CAP) break; // -> solo
        const float vx = ccx - tx, vy = ccy - ty, vz = ccz - tz;
        const float nrm = sqrtf(vx*vx + vy*vy + vz*vz);
        const float den = nrm + EPS_NORM;
        const float ax = vx / den, ay = vy / den, az = vz / den;
        const float b  = ax*ccx + ay*ccy + az*ccz;   // b = sum(a * closest)
        if (tid == 0) {
            const size_t oa = ((size_t)k * M + m) * 3;
            out_a[oa+0] = ax; out_a[oa+1] = ay; out_a[oa+2] = az;
            out_b[(size_t)k * M + m] = b;
            planes[4*k+0] = ax; planes[4*k+1] = ay;
            planes[4*k+2] = az; planes[4*k+3] = b;
        }
        ++k;
        if (k == MAX_ITERS) return;                  // all waves together
        if (ncount > 0) {
            scanN(ncount, ax, ay, az, b);
            ncount = ibc[1];
            ccx = fbc[0]; ccy = fbc[1]; ccz = fbc[2];
        }
    }

    // ---- SOLO mode: waves 1-15 park at the command barrier ----
    if (wv != 0) {
        for (;;) {
            __syncthreads();
            const int c = ibc[3];
            if (c == CMD_EXIT) return;
            buildNear(ibc[5]);                       // CMD_REFILL
        }
    }
    // wave 0:
    int scount = ncount;
    for (;;) {
        if (scount == 0) {
            if (lane == 0) { ibc[3] = CMD_REFILL; ibc[5] = k; }
            __syncthreads();
            buildNear(k);
            scount = ibc[1];
            ccx = fbc[0]; ccy = fbc[1]; ccz = fbc[2];
            if (ibc[4] == 0) {                       // truly empty
                if (lane == 0) ibc[3] = CMD_EXIT;
                __syncthreads();
                const float c0 = pc[0], c1 = pc[1], c2 = pc[2];
                const float vx = c0 - tx, vy = c1 - ty, vz = c2 - tz;
                const float nrm = sqrtf(vx*vx + vy*vy + vz*vz);
                const float den = nrm + EPS_NORM;
                const float ax = vx / den, ay = vy / den, az = vz / den;
                const float b  = ax*c0 + ay*c1 + az*c2;
                for (int q = lane; q < MAX_ITERS - k; q += 64) {
                    const int kk = k + q;
                    const size_t oa = ((size_t)kk * M + m) * 3;
                    out_a[oa+0] = ax; out_a[oa+1] = ay; out_a[oa+2] = az;
                    out_b[(size_t)kk * M + m] = b;
                }
                return;
            }
        }
        const float vx = ccx - tx, vy = ccy - ty, vz = ccz - tz;
        const float nrm = sqrtf(vx*vx + vy*vy + vz*vz);
        const float den = nrm + EPS_NORM;
        const float ax = vx / den, ay = vy / den, az = vz / den;
        const float b  = ax*ccx + ay*ccy + az*ccz;
        if (lane == 0) {
            const size_t oa = ((size_t)k * M + m) * 3;
            out_a[oa+0] = ax; out_a[oa+1] = ay; out_a[oa+2] = az;
            out_b[(size_t)k * M + m] = b;
            planes[4*k+0] = ax; planes[4*k+1] = ay;
            planes[4*k+2] = az; planes[4*k+3] = b;
        }
        ++k;
        if (k == MAX_ITERS) {
            if (lane == 0) ibc[3] = CMD_EXIT;
            __syncthreads();
            return;
        }
        if (scount > 0) {                            // wave-synchronous cut
            float dmin = INFINITY; int imin = 0;
            float mx = 0.f, my = 0.f, mz = 0.f;
            int wcur = 0;
            const int old = scount;
            for (int g0 = 0; g0 < old; g0 += 256) {
                float X[4], Y[4], Z[4], D[4]; int J[4];
                uint32_t km = 0;
                #pragma unroll
                for (int u = 0; u < 4; ++u) {        // read group fully first
                    const int e = g0 + u * 64 + lane;
                    if (e < old) {
                        X[u] = sx[e]; Y[u] = sy[e]; Z[u] = sz[e]; J[u] = sid[e];
                        float dt = ax*X[u] + ay*Y[u] + az*Z[u] - b;
                        if (dt < EPS_SEP) {
                            km |= (1u << u);
                            float p2 = X[u]*X[u] + Y[u]*Y[u] + Z[u]*Z[u];
                            float tp = tx*X[u] + ty*Y[u] + tz*Z[u];
                            D[u] = t2 + p2 - 2.0f*tp;
                        }
                    }
                }
                #pragma unroll
                for (int u = 0; u < 4; ++u) {        // compacted writes after
                    unsigned long long bal = __ballot(((km >> u) & 1u) != 0u);
                    int pos = wcur + (int)__popcll(bal & ((1ull << lane) - 1ull));
                    if ((km >> u) & 1u) {
                        sx[pos] = X[u]; sy[pos] = Y[u]; sz[pos] = Z[u]; sid[pos] = J[u];
                        if (D[u] < dmin || (D[u] == dmin && J[u] < imin)) {
                            dmin = D[u]; imin = J[u]; mx = X[u]; my = Y[u]; mz = Z[u];
                        }
                    }
                    wcur += (int)__popcll(bal);
                }   // writes stay < wcur <= g0+256 = next group's start
            }
            #pragma unroll
            for (int off = 32; off > 0; off >>= 1) {
                float od = __shfl_down(dmin, off, 64);
                int   oi = __shfl_down(imin, off, 64);
                float ox = __shfl_down(mx, off, 64);
                float oy = __shfl_down(my, off, 64);
                float oz = __shfl_down(mz, off, 64);
                if (od < dmin || (od == dmin && oi < imin)) {
                    dmin = od; imin = oi; mx = ox; my = oy; mz = oz;
                }
            }
            ccx = __shfl(mx, 0, 64);
            ccy = __shfl(my, 0, 64);
            ccz = __shfl(mz, 0, 64);
            scount = wcur;                           // uniform across lanes
        }
    }
}

extern "C" void kernel_launch(void* const* d_in, const int* in_sizes, int n_in,
                              void* d_out, int out_size, void* d_ws, size_t ws_size,
                              hipStream_t stream) {
    const float* pc = (const float*)d_in[0];
    const float* tg = (const float*)d_in[1];
    float* out = (float*)d_out;
    const int N = in_sizes[0] / 3;
    const int M = in_sizes[1] / 3;
    const int stepsA = (N + BLOCK * PT - 1) / (BLOCK * PT);

    const size_t words = (size_t)4 * NEAR_CAP        // SoA
                       + 52 * 4                      // padded planes
                       + 4 * NW + NW + NW            // red_* float, red_i, wsum
                       + 6 + 3 + 1;                  // ibc, fbc, cur
    const size_t smem = words * 4;                   // ~153 KB
    hipFuncSetAttribute((const void*)convex_plane_kernel,
                        hipFuncAttributeMaxDynamicSharedMemorySize, (int)smem);
    convex_plane_kernel<<<M, BLOCK, smem, stream>>>(pc, tg, out, N, M, stepsA);
}

// Round 10
// 596.084 us; speedup vs baseline: 1.8406x; 1.8341x over previous
//
#include <hip/hip_runtime.h>
#include <stdint.h>
#include <math.h>

// Match numpy's non-fused multiply-add rounding: a wrong argmin or a boundary
// mask flip cascades into O(1) output error. R1-R9 passed with absmax 0.0
// using exactly these expression forms — keep them everywhere.
#pragma clang fp contract(off)

#define BLOCK 1024
#define NW (BLOCK / 64)
#define PT 4                     // points/thread/step in full passes (slab-major)
                                 // R10: 8->4. R8/R9 spilled px/py/pz[8]+planes
                                 // at the 64-VGPR cap -> 2.1 GB scratch writes.
#define PB 4                     // entries/thread/step in block near-engine
#define MAX_ITERS 50
#define NEAR_CAP 9472            // LDS SoA capacity (16 B/entry)
#define SOLO_CAP 2048            // below this, wave 0 runs alone
#define HB 4096                  // d2 histogram bins (top 12 bits of f32)
#define EPS_NORM 1e-8f
#define EPS_SEP (-1e-6f)
#define CMD_REFILL 1
#define CMD_EXIT 2

// R9 post-mortem: __launch_bounds__(BLOCK,4) did NOT raise the VGPR cap
// (VGPR_Count stayed 64, spill traffic identical). R10 forces the budget via
// the backend attribute amdgpu_waves_per_eu(4,4) (budget = 512/4 = 128, the
// max a 16-wave block can launch with) AND drops PT to 4 so worst-case
// pressure fits even a 64-reg cap. Algorithm unchanged from R8/R9 (validated:
// FETCH == 2 full passes/block, absmax 0.0).
//
// Algorithm: planes depend only on the closest survivor; far points matter
// only after all nearer ones die. 2 full passes (d2 histogram -> threshold;
// collect nearest <=NEAR_CAP survivors into LDS SoA + exact argmin over ALL
// survivors), then all iterations run on the LDS near set. On empty: refill
// (same 2 passes + stored-plane early-exit tests, 4 planes register-chunked).
// Waves 1-15 park at a barrier command protocol during the solo phase.
__global__ __launch_bounds__(BLOCK)
__attribute__((amdgpu_waves_per_eu(4, 4)))
void convex_plane_kernel(
    const float* __restrict__ pc, const float* __restrict__ tg,
    float* __restrict__ out, int N, int M, int stepsA)
{
    extern __shared__ uint32_t smem[];
    const int tid  = threadIdx.x;
    const int lane = tid & 63;
    const int wv   = tid >> 6;
    const int m    = blockIdx.x;

    float* sx     = (float*)smem;                 // [NEAR_CAP]
    float* sy     = sx + NEAR_CAP;                // [NEAR_CAP]
    float* sz     = sy + NEAR_CAP;                // [NEAR_CAP]
    int*   sid    = (int*)(sz + NEAR_CAP);        // [NEAR_CAP]
    float* planes = (float*)(sid + NEAR_CAP);     // [52*4] padded, 16B-aligned
    float* red_d  = planes + 52 * 4;              // [NW]
    float* red_x  = red_d + NW;                   // [NW]
    float* red_y  = red_x + NW;                   // [NW]
    float* red_z  = red_y + NW;                   // [NW]
    int*   red_i  = (int*)(red_z + NW);           // [NW]
    int*   wsum   = red_i + NW;                   // [NW]
    int*   ibc    = wsum + NW;                    // [6] {idx,ncount,Kthr,cmd,totSurv,karg}
    float* fbc    = (float*)(ibc + 6);            // [3] argmin coords
    int*   cur    = (int*)(fbc + 3);              // [1] append cursor
    int*   hist   = (int*)sx;                     // aliases sx during buildNear
    const float4* pl4 = (const float4*)planes;

    const float tx = tg[3*m+0], ty = tg[3*m+1], tz = tg[3*m+2];
    const float t2 = tx*tx + ty*ty + tz*tz;

    float* out_a = out;
    float* out_b = out + (size_t)MAX_ITERS * (size_t)M * 3;

    // pad planes: {0,0,0,+inf} never separates (dt = -inf < EPS_SEP), so the
    // refill's 4-plane register chunks can always test a full group of 4.
    if (tid < 52) {
        planes[4*tid+0] = 0.f; planes[4*tid+1] = 0.f;
        planes[4*tid+2] = 0.f; planes[4*tid+3] = INFINITY;
    }

    // block-wide: lexicographic (d2,idx) argmin + coords + survivor-total;
    // results in ibc/fbc for ALL threads (barrier-protected).
    auto finishC = [&](float dmin, int imin, float mx, float my, float mz,
                       int mycnt) {
        #pragma unroll
        for (int off = 32; off > 0; off >>= 1) {
            float od = __shfl_down(dmin, off, 64);
            int   oi = __shfl_down(imin, off, 64);
            float ox = __shfl_down(mx, off, 64);
            float oy = __shfl_down(my, off, 64);
            float oz = __shfl_down(mz, off, 64);
            int   oc = __shfl_down(mycnt, off, 64);
            if (od < dmin || (od == dmin && oi < imin)) {
                dmin = od; imin = oi; mx = ox; my = oy; mz = oz;
            }
            mycnt += oc;
        }
        if (lane == 0) {
            red_d[wv] = dmin; red_i[wv] = imin;
            red_x[wv] = mx; red_y[wv] = my; red_z[wv] = mz; wsum[wv] = mycnt;
        }
        __syncthreads();
        if (wv == 0) {
            float bd = (lane < NW) ? red_d[lane] : INFINITY;
            int   bi = (lane < NW) ? red_i[lane] : 0;
            float bx = (lane < NW) ? red_x[lane] : 0.f;
            float by = (lane < NW) ? red_y[lane] : 0.f;
            float bz = (lane < NW) ? red_z[lane] : 0.f;
            int   c  = (lane < NW) ? wsum[lane]  : 0;
            #pragma unroll
            for (int off = 8; off > 0; off >>= 1) {
                float od = __shfl_down(bd, off, 64);
                int   oi = __shfl_down(bi, off, 64);
                float ox = __shfl_down(bx, off, 64);
                float oy = __shfl_down(by, off, 64);
                float oz = __shfl_down(bz, off, 64);
                int   oc = __shfl_down(c, off, 64);
                if (od < bd || (od == bd && oi < bi)) {
                    bd = od; bi = oi; bx = ox; by = oy; bz = oz;
                }
                c += oc;
            }
            if (lane == 0) {
                ibc[0] = bi; ibc[1] = cur[0]; ibc[4] = c;
                fbc[0] = bx; fbc[1] = by; fbc[2] = bz;
            }
        }
        __syncthreads();
    };

    // Unified build/refill (ALL waves): pass A histograms d2 of survivors of
    // planes[0..kplanes); threshold = nearest <=NEAR_CAP; pass B collects the
    // near set into SoA and the exact argmin over ALL survivors.
    auto buildNear = [&](int kplanes) {
        for (int h = tid; h < HB; h += BLOCK) hist[h] = 0;
        __syncthreads();
        // ---- pass A ----
        for (int s = 0; s < stepsA; ++s) {
            const int ib = s * PT * BLOCK + tid;
            uint32_t live = 0;
            float px[PT], py[PT], pz[PT];
            #pragma unroll
            for (int j = 0; j < PT; ++j) {
                const int i = ib + j * BLOCK;
                if (i < N) {
                    live |= (1u << j);
                    const float* p = pc + 3 * (size_t)i;
                    px[j] = p[0]; py[j] = p[1]; pz[j] = p[2];
                }
            }
            for (int q0 = 0; q0 < kplanes && live; q0 += 4) {
                float4 a0 = pl4[q0], a1 = pl4[q0+1], a2 = pl4[q0+2], a3 = pl4[q0+3];
                #pragma unroll
                for (int j = 0; j < PT; ++j) if ((live >> j) & 1u) {
                    float d0 = a0.x*px[j] + a0.y*py[j] + a0.z*pz[j] - a0.w;
                    float d1 = a1.x*px[j] + a1.y*py[j] + a1.z*pz[j] - a1.w;
                    float d2t = a2.x*px[j] + a2.y*py[j] + a2.z*pz[j] - a2.w;
                    float d3 = a3.x*px[j] + a3.y*py[j] + a3.z*pz[j] - a3.w;
                    if (d0 >= EPS_SEP || d1 >= EPS_SEP || d2t >= EPS_SEP || d3 >= EPS_SEP)
                        live &= ~(1u << j);
                }
            }
            #pragma unroll
            for (int j = 0; j < PT; ++j) if ((live >> j) & 1u) {
                float p2 = px[j]*px[j] + py[j]*py[j] + pz[j]*pz[j];
                float tp = tx*px[j] + ty*py[j] + tz*pz[j];
                float d2 = t2 + p2 - 2.0f*tp;        // reference's exact form
                atomicAdd(&hist[(int)(__float_as_uint(d2) >> 20)], 1);
            }
        }
        __syncthreads();
        // ---- threshold: largest prefix with cumulative <= NEAR_CAP ----
        const int b0 = tid * (HB / BLOCK);           // 4 bins/thread
        const int h0 = hist[b0], h1 = hist[b0+1], h2 = hist[b0+2], h3 = hist[b0+3];
        const int ls = h0 + h1 + h2 + h3;
        int incl = ls;
        #pragma unroll
        for (int off = 1; off < 64; off <<= 1) {
            int o = __shfl_up(incl, off, 64);
            if (lane >= off) incl += o;
        }
        if (lane == 63) wsum[wv] = incl;
        if (tid == 0) ibc[2] = HB;                   // default: keep all
        __syncthreads();
        if (wv == 0 && lane < NW) {
            int v = wsum[lane];
            int i2 = v;
            #pragma unroll
            for (int off = 1; off < NW; off <<= 1) {
                int o = __shfl_up(i2, off, 64);
                if (lane >= off) i2 += o;
            }
            wsum[lane] = i2 - v;                     // exclusive wave base
        }
        __syncthreads();
        int ex = wsum[wv] + incl - ls;               // excl prefix before b0
        int c = ex;                                  // exactly one crossing
        if (c <= NEAR_CAP && c + h0 > NEAR_CAP) ibc[2] = b0;
        c += h0; if (c <= NEAR_CAP && c + h1 > NEAR_CAP) ibc[2] = b0 + 1;
        c += h1; if (c <= NEAR_CAP && c + h2 > NEAR_CAP) ibc[2] = b0 + 2;
        c += h2; if (c <= NEAR_CAP && c + h3 > NEAR_CAP) ibc[2] = b0 + 3;
        if (tid == 0) cur[0] = 0;
        __syncthreads();                             // hist (sx) dead after this
        const int Kthr = ibc[2];
        // ---- pass B: collect near + argmin over ALL survivors ----
        float dmin = INFINITY; int imin = 0;
        float mx = 0.f, my = 0.f, mz = 0.f;
        int mycnt = 0;
        for (int s = 0; s < stepsA; ++s) {
            const int ib = s * PT * BLOCK + tid;
            uint32_t live = 0;
            float px[PT], py[PT], pz[PT];
            #pragma unroll
            for (int j = 0; j < PT; ++j) {
                const int i = ib + j * BLOCK;
                if (i < N) {
                    live |= (1u << j);
                    const float* p = pc + 3 * (size_t)i;
                    px[j] = p[0]; py[j] = p[1]; pz[j] = p[2];
                }
            }
            for (int q0 = 0; q0 < kplanes && live; q0 += 4) {
                float4 a0 = pl4[q0], a1 = pl4[q0+1], a2 = pl4[q0+2], a3 = pl4[q0+3];
                #pragma unroll
                for (int j = 0; j < PT; ++j) if ((live >> j) & 1u) {
                    float d0 = a0.x*px[j] + a0.y*py[j] + a0.z*pz[j] - a0.w;
                    float d1 = a1.x*px[j] + a1.y*py[j] + a1.z*pz[j] - a1.w;
                    float d2t = a2.x*px[j] + a2.y*py[j] + a2.z*pz[j] - a2.w;
                    float d3 = a3.x*px[j] + a3.y*py[j] + a3.z*pz[j] - a3.w;
                    if (d0 >= EPS_SEP || d1 >= EPS_SEP || d2t >= EPS_SEP || d3 >= EPS_SEP)
                        live &= ~(1u << j);
                }
            }
            mycnt += (int)__popc(live);
            #pragma unroll
            for (int j = 0; j < PT; ++j) {
                bool nearkeep = false;
                float d2 = 0.f;
                if ((live >> j) & 1u) {
                    float p2 = px[j]*px[j] + py[j]*py[j] + pz[j]*pz[j];
                    float tp = tx*px[j] + ty*py[j] + tz*pz[j];
                    d2 = t2 + p2 - 2.0f*tp;          // bitwise same as pass A
                    const int i = ib + j * BLOCK;
                    if (d2 < dmin || (d2 == dmin && i < imin)) {
                        dmin = d2; imin = i; mx = px[j]; my = py[j]; mz = pz[j];
                    }
                    nearkeep = ((int)(__float_as_uint(d2) >> 20) < Kthr);
                }
                unsigned long long bal = __ballot(nearkeep);
                if (bal) {                            // wave-uniform
                    int base = 0;
                    if (lane == 0) base = atomicAdd(cur, (int)__popcll(bal));
                    base = __shfl(base, 0, 64);
                    if (nearkeep) {
                        int pos = base + (int)__popcll(bal & ((1ull << lane) - 1ull));
                        if (pos < NEAR_CAP) {
                            sx[pos] = px[j]; sy[pos] = py[j]; sz[pos] = pz[j];
                            sid[pos] = ib + j * BLOCK;
                        }
                    }
                }
            }
        }
        finishC(dmin, imin, mx, my, mz, mycnt);
    };

    // Block near-engine: cut SoA in place (scanB-proven discipline).
    auto scanN = [&](int count, float ax, float ay, float az, float b) {
        if (tid == 0) cur[0] = 0;
        __syncthreads();
        float dmin = INFINITY; int imin = 0;
        float mx = 0.f, my = 0.f, mz = 0.f;
        const int per = BLOCK * PB;
        const int bsteps = (count + per - 1) / per;
        for (int s = 0; s < bsteps; ++s) {
            float X[PB], Y[PB], Z[PB], D[PB]; int J[PB];
            uint32_t keepm = 0;
            #pragma unroll
            for (int q = 0; q < PB; ++q) {
                const int e = s * per + q * BLOCK + tid;  // lane-stride 1
                if (e < count) {
                    float px = sx[e], py = sy[e], pz = sz[e];
                    X[q] = px; Y[q] = py; Z[q] = pz; J[q] = sid[e];
                    float dt = ax*px + ay*py + az*pz - b;
                    if (dt < EPS_SEP) {
                        keepm |= (1u << q);
                        float p2 = px*px + py*py + pz*pz;
                        float tp = tx*px + ty*py + tz*pz;
                        D[q] = t2 + p2 - 2.0f*tp;
                    }
                }
            }
            __syncthreads();                         // reads before appends
            int c = (int)__popc(keepm);
            int incl = c;
            #pragma unroll
            for (int off = 1; off < 64; off <<= 1) {
                int o = __shfl_up(incl, off, 64);
                if (lane >= off) incl += o;
            }
            const int excl = incl - c;
            const int tot  = __shfl(incl, 63, 64);
            int wb = 0;
            if (lane == 0) wb = atomicAdd(cur, tot);
            wb = __shfl(wb, 0, 64);
            int pos = wb + excl;
            #pragma unroll
            for (int q = 0; q < PB; ++q) if ((keepm >> q) & 1u) {
                sx[pos] = X[q]; sy[pos] = Y[q]; sz[pos] = Z[q]; sid[pos] = J[q];
                if (D[q] < dmin || (D[q] == dmin && J[q] < imin)) {
                    dmin = D[q]; imin = J[q]; mx = X[q]; my = Y[q]; mz = Z[q];
                }
                ++pos;
            }
        }
        finishC(dmin, imin, mx, my, mz, 0);
    };

    // ---- initial build (kplanes = 0) ----
    buildNear(0);
    int   ncount = ibc[1];
    float ccx = fbc[0], ccy = fbc[1], ccz = fbc[2];
    int k = 0;

    // ---- BLOCK mode ----
    for (;;) {
        if (ncount == 0) {
            buildNear(k);                            // planes 0..k-1 stored
            ncount = ibc[1];
            ccx = fbc[0]; ccy = fbc[1]; ccz = fbc[2];
            if (ibc[4] == 0) {                       // truly empty: pc[0] tail
                const float c0 = pc[0], c1 = pc[1], c2 = pc[2];
                const float vx = c0 - tx, vy = c1 - ty, vz = c2 - tz;
                const float nrm = sqrtf(vx*vx + vy*vy + vz*vz);
                const float den = nrm + EPS_NORM;
                const float ax = vx / den, ay = vy / den, az = vz / den;
                const float b  = ax*c0 + ay*c1 + az*c2;
                for (int q = tid; q < MAX_ITERS - k; q += BLOCK) {
                    const int kk = k + q;
                    const size_t oa = ((size_t)kk * M + m) * 3;
                    out_a[oa+0] = ax; out_a[oa+1] = ay; out_a[oa+2] = az;
                    out_b[(size_t)kk * M + m] = b;
                }
                return;
            }
        }
        if (ncount > 0 && ncount <= SOLO_CAP) break; // -> solo
        const float vx = ccx - tx, vy = ccy - ty, vz = ccz - tz;
        const float nrm = sqrtf(vx*vx + vy*vy + vz*vz);
        const float den = nrm + EPS_NORM;
        const float ax = vx / den, ay = vy / den, az = vz / den;
        const float b  = ax*ccx + ay*ccy + az*ccz;   // b = sum(a * closest)
        if (tid == 0) {
            const size_t oa = ((size_t)k * M + m) * 3;
            out_a[oa+0] = ax; out_a[oa+1] = ay; out_a[oa+2] = az;
            out_b[(size_t)k * M + m] = b;
            planes[4*k+0] = ax; planes[4*k+1] = ay;
            planes[4*k+2] = az; planes[4*k+3] = b;
        }
        ++k;
        if (k == MAX_ITERS) return;                  // all waves together
        if (ncount > 0) {
            scanN(ncount, ax, ay, az, b);
            ncount = ibc[1];
            ccx = fbc[0]; ccy = fbc[1]; ccz = fbc[2];
        }
    }

    // ---- SOLO mode: waves 1-15 park at the command barrier ----
    if (wv != 0) {
        for (;;) {
            __syncthreads();
            const int c = ibc[3];
            if (c == CMD_EXIT) return;
            buildNear(ibc[5]);                       // CMD_REFILL
        }
    }
    // wave 0:
    int scount = ncount;
    for (;;) {
        if (scount == 0) {
            if (lane == 0) { ibc[3] = CMD_REFILL; ibc[5] = k; }
            __syncthreads();
            buildNear(k);
            scount = ibc[1];
            ccx = fbc[0]; ccy = fbc[1]; ccz = fbc[2];
            if (ibc[4] == 0) {                       // truly empty
                if (lane == 0) ibc[3] = CMD_EXIT;
                __syncthreads();
                const float c0 = pc[0], c1 = pc[1], c2 = pc[2];
                const float vx = c0 - tx, vy = c1 - ty, vz = c2 - tz;
                const float nrm = sqrtf(vx*vx + vy*vy + vz*vz);
                const float den = nrm + EPS_NORM;
                const float ax = vx / den, ay = vy / den, az = vz / den;
                const float b  = ax*c0 + ay*c1 + az*c2;
                for (int q = lane; q < MAX_ITERS - k; q += 64) {
                    const int kk = k + q;
                    const size_t oa = ((size_t)kk * M + m) * 3;
                    out_a[oa+0] = ax; out_a[oa+1] = ay; out_a[oa+2] = az;
                    out_b[(size_t)kk * M + m] = b;
                }
                return;
            }
        }
        const float vx = ccx - tx, vy = ccy - ty, vz = ccz - tz;
        const float nrm = sqrtf(vx*vx + vy*vy + vz*vz);
        const float den = nrm + EPS_NORM;
        const float ax = vx / den, ay = vy / den, az = vz / den;
        const float b  = ax*ccx + ay*ccy + az*ccz;
        if (lane == 0) {
            const size_t oa = ((size_t)k * M + m) * 3;
            out_a[oa+0] = ax; out_a[oa+1] = ay; out_a[oa+2] = az;
            out_b[(size_t)k * M + m] = b;
            planes[4*k+0] = ax; planes[4*k+1] = ay;
            planes[4*k+2] = az; planes[4*k+3] = b;
        }
        ++k;
        if (k == MAX_ITERS) {
            if (lane == 0) ibc[3] = CMD_EXIT;
            __syncthreads();
            return;
        }
        if (scount > 0) {                            // wave-synchronous cut
            float dmin = INFINITY; int imin = 0;
            float mx = 0.f, my = 0.f, mz = 0.f;
            int wcur = 0;
            const int old = scount;
            for (int g0 = 0; g0 < old; g0 += 256) {
                float X[4], Y[4], Z[4], D[4]; int J[4];
                uint32_t km = 0;
                #pragma unroll
                for (int u = 0; u < 4; ++u) {        // read group fully first
                    const int e = g0 + u * 64 + lane;
                    if (e < old) {
                        X[u] = sx[e]; Y[u] = sy[e]; Z[u] = sz[e]; J[u] = sid[e];
                        float dt = ax*X[u] + ay*Y[u] + az*Z[u] - b;
                        if (dt < EPS_SEP) {
                            km |= (1u << u);
                            float p2 = X[u]*X[u] + Y[u]*Y[u] + Z[u]*Z[u];
                            float tp = tx*X[u] + ty*Y[u] + tz*Z[u];
                            D[u] = t2 + p2 - 2.0f*tp;
                        }
                    }
                }
                #pragma unroll
                for (int u = 0; u < 4; ++u) {        // compacted writes after
                    unsigned long long bal = __ballot(((km >> u) & 1u) != 0u);
                    int pos = wcur + (int)__popcll(bal & ((1ull << lane) - 1ull));
                    if ((km >> u) & 1u) {
                        sx[pos] = X[u]; sy[pos] = Y[u]; sz[pos] = Z[u]; sid[pos] = J[u];
                        if (D[u] < dmin || (D[u] == dmin && J[u] < imin)) {
                            dmin = D[u]; imin = J[u]; mx = X[u]; my = Y[u]; mz = Z[u];
                        }
                    }
                    wcur += (int)__popcll(bal);
                }   // writes stay < wcur <= g0+256 = next group's start
            }
            #pragma unroll
            for (int off = 32; off > 0; off >>= 1) {
                float od = __shfl_down(dmin, off, 64);
                int   oi = __shfl_down(imin, off, 64);
                float ox = __shfl_down(mx, off, 64);
                float oy = __shfl_down(my, off, 64);
                float oz = __shfl_down(mz, off, 64);
                if (od < dmin || (od == dmin && oi < imin)) {
                    dmin = od; imin = oi; mx = ox; my = oy; mz = oz;
                }
            }
            ccx = __shfl(mx, 0, 64);
            ccy = __shfl(my, 0, 64);
            ccz = __shfl(mz, 0, 64);
            scount = wcur;                           // uniform across lanes
        }
    }
}

extern "C" void kernel_launch(void* const* d_in, const int* in_sizes, int n_in,
                              void* d_out, int out_size, void* d_ws, size_t ws_size,
                              hipStream_t stream) {
    const float* pc = (const float*)d_in[0];
    const float* tg = (const float*)d_in[1];
    float* out = (float*)d_out;
    const int N = in_sizes[0] / 3;
    const int M = in_sizes[1] / 3;
    const int stepsA = (N + BLOCK * PT - 1) / (BLOCK * PT);

    const size_t words = (size_t)4 * NEAR_CAP        // SoA
                       + 52 * 4                      // padded planes
                       + 4 * NW + NW + NW            // red_* float, red_i, wsum
                       + 6 + 3 + 1;                  // ibc, fbc, cur
    const size_t smem = words * 4;                   // ~153 KB
    hipFuncSetAttribute((const void*)convex_plane_kernel,
                        hipFuncAttributeMaxDynamicSharedMemorySize, (int)smem);
    convex_plane_kernel<<<M, BLOCK, smem, stream>>>(pc, tg, out, N, M, stepsA);
}